// Round 6
// baseline (1309.759 us; speedup 1.0000x reference)
//
#include <hip/hip_runtime.h>
#include <hip/hip_bf16.h>

#define NN 100000
#define EE 1600000

typedef unsigned short u16;
typedef unsigned int   u32;
typedef short short8 __attribute__((ext_vector_type(8)));
typedef float v4f    __attribute__((ext_vector_type(4)));

__device__ __forceinline__ float b2f(u16 h){ u32 u = ((u32)h) << 16; return __builtin_bit_cast(float, u); }
__device__ __forceinline__ float lo2f(u32 u){ return __builtin_bit_cast(float, u << 16); }
__device__ __forceinline__ float hi2f(u32 u){ return __builtin_bit_cast(float, u & 0xffff0000u); }
__device__ __forceinline__ u16   f2b(float f){ __hip_bfloat16 h = __float2bfloat16(f); return __builtin_bit_cast(u16, h); }
__device__ __forceinline__ float ldx(const void* p, long i, int fm){
  return fm ? ((const float*)p)[i] : b2f(((const u16*)p)[i]);
}
__device__ __forceinline__ float i2f(int v){ return __builtin_bit_cast(float, v); }

// ---------------- dtype detection (parallel) ----------------
__global__ void k_detect(const void* __restrict__ x, const void* __restrict__ nonlab,
                         int* __restrict__ flags){
  __shared__ int s_bad, s_ni, s_nf, s_nb;
  int t = threadIdx.x;
  if (t == 0){ s_bad = 0; s_ni = 0; s_nf = 0; s_nb = 0; }
  __syncthreads();
  u32 w = ((const u32*)x)[t];
  u32 lo = w & 0xffffu, ex = (lo >> 7) & 0xffu;
  if (lo != 0u && (ex < 100u || ex > 140u)) atomicAdd(&s_bad, 1);
  if (t < 64){
    u32 v = ((const u32*)nonlab)[t];
    if (v > 1u) atomicAdd(&s_ni, 1);
    if (v != 0u && v != 0x3F800000u) atomicAdd(&s_nf, 1);
  }
  if (t < 128){
    u16 h = ((const u16*)nonlab)[t];
    if (h != 0 && h != 0x3F80) atomicAdd(&s_nb, 1);
  }
  __syncthreads();
  if (t == 0){
    flags[0] = (s_bad > 32) ? 1 : 0;
    flags[1] = (s_ni == 0) ? 1 : ((s_nf == 0) ? 3 : ((s_nb == 0) ? 2 : 0));
  }
}

// ---------------- CSR build ----------------
// count + per-edge rank (atomicAdd return value = rank within row)
__global__ void k_count(const int* __restrict__ ei, int* __restrict__ cnt, int* __restrict__ rank){
  int e = blockIdx.x * 256 + threadIdx.x;
  if (e < EE) rank[e] = atomicAdd(&cnt[ei[e]], 1);
}

#define SCAN_C 1024
__global__ void k_scan1(const int* __restrict__ cnt, int* __restrict__ part){
  __shared__ int red[256];
  int b = blockIdx.x, t = threadIdx.x;
  int base = b * SCAN_C + t * 4;
  int s = 0;
  #pragma unroll
  for (int j = 0; j < 4; ++j){ int i = base + j; if (i < NN) s += cnt[i]; }
  red[t] = s; __syncthreads();
  for (int o = 128; o; o >>= 1){ if (t < o) red[t] += red[t + o]; __syncthreads(); }
  if (t == 0) part[b] = red[0];
}
__global__ void k_scan2(int* __restrict__ part, int* __restrict__ rowptr, int nb){
  __shared__ int l[128];
  int t = threadIdx.x;
  int v = (t < nb) ? part[t] : 0;
  l[t] = v; __syncthreads();
  for (int o = 1; o < 128; o <<= 1){
    int x = (t >= o) ? l[t - o] : 0; __syncthreads();
    l[t] += x; __syncthreads();
  }
  if (t < nb) part[t] = l[t] - v;          // exclusive
  if (t == nb - 1) rowptr[NN] = l[t];      // total == EE
}
__global__ void k_scan3(const int* __restrict__ cnt, const int* __restrict__ part,
                        int* __restrict__ rowptr){
  __shared__ int lds[256];
  int b = blockIdx.x, t = threadIdx.x;
  int base = b * SCAN_C + t * 4;
  int v[4]; int s = 0;
  #pragma unroll
  for (int j = 0; j < 4; ++j){ int i = base + j; v[j] = (i < NN) ? cnt[i] : 0; s += v[j]; }
  lds[t] = s; __syncthreads();
  for (int o = 1; o < 256; o <<= 1){
    int x = (t >= o) ? lds[t - o] : 0; __syncthreads();
    lds[t] += x; __syncthreads();
  }
  int excl = lds[t] - s + part[b];
  #pragma unroll
  for (int j = 0; j < 4; ++j){
    int i = base + j;
    if (i < NN){ rowptr[i] = excl; excl += v[j]; }
  }
}
// atomic-free scatter: pos = rowptr[row] + rank[e]
__global__ void k_scatter(const int* __restrict__ ei, const void* __restrict__ ew,
                          const int* __restrict__ rowptr, const int* __restrict__ rank,
                          int2* __restrict__ cpk, const int* __restrict__ flags){
  int e = blockIdx.x * 256 + threadIdx.x;
  if (e >= EE) return;
  int fm = flags[0];
  int r = ei[e], c = ei[EE + e];
  int pos = rowptr[r] + rank[e];
  float wv = ldx(ew, e, fm);
  cpk[pos] = make_int2(c, __builtin_bit_cast(int, wv));
}

// ---------------- SpMM: one wave per row, predicated 16-deep edge batching ----------------
template<int D, bool EXT>
__global__ __launch_bounds__(256) void k_spmm(const void* __restrict__ in, u16* __restrict__ out,
                       const int* __restrict__ rowptr, const int2* __restrict__ cpk,
                       const int* __restrict__ flags){
  int wid  = blockIdx.x * 4 + (threadIdx.x >> 6);
  int lane = threadIdx.x & 63;
  if (wid >= NN) return;
  int fm = EXT ? flags[0] : 0;
  int s = rowptr[wid], e = rowptr[wid + 1];
  float a0 = 0.f, a1 = 0.f, a2 = 0.f;
  if (EXT && fm){
    const float* fin = (const float*)in;
    for (int j = s; j < e; j += 16){
      int2 p[16];
      #pragma unroll
      for (int q = 0; q < 16; ++q){ int jj = j + q; p[q] = cpk[jj < e ? jj : e - 1]; }
      float2 v[16];
      #pragma unroll
      for (int q = 0; q < 16; ++q) v[q] = *(const float2*)(fin + (long)p[q].x * D + 2 * lane);
      #pragma unroll
      for (int q = 0; q < 16; ++q){
        float wt = (j + q < e) ? i2f(p[q].y) : 0.f;
        a0 = fmaf(wt, v[q].x, a0);
        a1 = fmaf(wt, v[q].y, a1);
      }
    }
  } else {
    const u16* uin = (const u16*)in;
    for (int j = s; j < e; j += 16){
      int2 p[16];
      #pragma unroll
      for (int q = 0; q < 16; ++q){ int jj = j + q; p[q] = cpk[jj < e ? jj : e - 1]; }
      u32 u[16]; u16 x2[16];
      #pragma unroll
      for (int q = 0; q < 16; ++q){
        long base = (long)p[q].x * D;
        u[q] = *(const u32*)(uin + base + 2 * lane);
        if (D == 192) x2[q] = uin[base + 128 + lane];
      }
      #pragma unroll
      for (int q = 0; q < 16; ++q){
        float wt = (j + q < e) ? i2f(p[q].y) : 0.f;
        a0 = fmaf(wt, lo2f(u[q]), a0);
        a1 = fmaf(wt, hi2f(u[q]), a1);
        if (D == 192) a2 = fmaf(wt, b2f(x2[q]), a2);
      }
    }
  }
  u16* q = out + (long)wid * D;
  *(u32*)(q + 2 * lane) = (u32)f2b(a0) | ((u32)f2b(a1) << 16);
  if (D == 192) q[128 + lane] = f2b(a2);
}

// ---------------- generic MFMA GEMM (plain A, optional final-dtype out) ----------------
template<int K, int DOUT, int CT, int RTW, bool RELU, int OMODE>
__global__ __launch_bounds__(256) void k_mm(const u16* __restrict__ A, const void* __restrict__ W,
     const void* __restrict__ bias, void* __restrict__ outv, const int* __restrict__ flags){
  constexpr int STEPS = K / 32;
  constexpr int G = DOUT / (16 * CT);
  constexpr int CHUNKS = 6250 / RTW;
  int wid = blockIdx.x * 4 + (threadIdx.x >> 6);
  if (wid >= G * CHUNKS) return;          // wave-uniform exit
  int g = wid % G; long chunk = wid / G;
  int lane = threadIdx.x & 63, n = lane & 15, q = lane >> 4;
  int colOff = g * CT * 16;
  int fm = flags[0];

  short8 B[CT][STEPS];
  float bv[CT];
  #pragma unroll
  for (int ct = 0; ct < CT; ++ct){
    int col = colOff + ct * 16 + n;
    bv[ct] = ldx(bias, col, fm);
    #pragma unroll
    for (int s = 0; s < STEPS; ++s){
      short8 t;
      #pragma unroll
      for (int j = 0; j < 8; ++j){
        int k = s * 32 + q * 8 + j;
        long wi = (long)k * DOUT + col;
        t[j] = fm ? (short)f2b(((const float*)W)[wi]) : (short)((const u16*)W)[wi];
      }
      B[ct][s] = t;
    }
  }

  for (int rt = 0; rt < RTW; ++rt){
    long rowbase = (chunk * RTW + rt) * 16;
    long arow = rowbase + n;
    v4f acc[CT] = {};
    #pragma unroll
    for (int s = 0; s < STEPS; ++s){
      short8 a = *(const short8*)(A + arow * K + s * 32 + q * 8);
      #pragma unroll
      for (int ct = 0; ct < CT; ++ct)
        acc[ct] = __builtin_amdgcn_mfma_f32_16x16x32_bf16(a, B[ct][s], acc[ct], 0, 0, 0);
    }
    long orow = rowbase + q * 4;
    #pragma unroll
    for (int ct = 0; ct < CT; ++ct){
      int col = colOff + ct * 16 + n;
      #pragma unroll
      for (int r = 0; r < 4; ++r){
        float v = acc[ct][r] + bv[ct];
        if (RELU) v = fmaxf(v, 0.f);
        long oi = (orow + r) * (long)DOUT + col;
        if (OMODE == 1){
          if (fm) ((float*)outv)[oi] = v; else ((u16*)outv)[oi] = f2b(v);
        } else {
          ((u16*)outv)[oi] = f2b(v);
        }
      }
    }
  }
}

// ---------------- fused encoder mm + column-sum (h_enc never materialized) ----------------
// colsum( relu( concat(hemb[N,128], y[N,32]) @ Wxy[160,128] + bxy ) ) -> accum[128]
__global__ __launch_bounds__(256) void k_mmsum(const u16* __restrict__ A, const u16* __restrict__ Y,
     const void* __restrict__ W, const void* __restrict__ bias,
     float* __restrict__ accum, const int* __restrict__ flags){
  constexpr int STEPS = 5, CT = 4, RTW = 5;   // K=160, DOUT=128, G=2; waves = 2*1250 = 2500, grid 625 full
  __shared__ float cs[128];
  int t = threadIdx.x;
  if (t < 128) cs[t] = 0.f;
  __syncthreads();
  int wid = blockIdx.x * 4 + (t >> 6);
  int g = wid & 1; long chunk = wid >> 1;
  int lane = t & 63, n = lane & 15, q = lane >> 4;
  int colOff = g * 64;
  int fm = flags[0];

  short8 B[CT][STEPS];
  float bv[CT];
  #pragma unroll
  for (int ct = 0; ct < CT; ++ct){
    int col = colOff + ct * 16 + n;
    bv[ct] = ldx(bias, col, fm);
    #pragma unroll
    for (int s = 0; s < STEPS; ++s){
      short8 tt;
      #pragma unroll
      for (int j = 0; j < 8; ++j){
        int k = s * 32 + q * 8 + j;
        long wi = (long)k * 128 + col;
        tt[j] = fm ? (short)f2b(((const float*)W)[wi]) : (short)((const u16*)W)[wi];
      }
      B[ct][s] = tt;
    }
  }

  float csum[CT] = {0.f, 0.f, 0.f, 0.f};
  for (int rt = 0; rt < RTW; ++rt){
    long rowbase = (chunk * RTW + rt) * 16;
    long arow = rowbase + n;
    v4f acc[CT] = {};
    #pragma unroll
    for (int s = 0; s < STEPS; ++s){
      short8 a;
      if (s < 4) a = *(const short8*)(A + arow * 128 + s * 32 + q * 8);
      else       a = *(const short8*)(Y + arow * 32 + q * 8);
      #pragma unroll
      for (int ct = 0; ct < CT; ++ct)
        acc[ct] = __builtin_amdgcn_mfma_f32_16x16x32_bf16(a, B[ct][s], acc[ct], 0, 0, 0);
    }
    #pragma unroll
    for (int ct = 0; ct < CT; ++ct){
      #pragma unroll
      for (int r = 0; r < 4; ++r)
        csum[ct] += fmaxf(acc[ct][r] + bv[ct], 0.f);
    }
  }
  #pragma unroll
  for (int ct = 0; ct < CT; ++ct){
    float v = csum[ct];
    v += __shfl_xor(v, 16);
    v += __shfl_xor(v, 32);
    if (q == 0) atomicAdd(&cs[colOff + ct * 16 + n], v);
  }
  __syncthreads();
  if (t < 128) atomicAdd(&accum[t], cs[t]);
}

// ---------------- fused decoder mm + row-norm + z-concat ----------------
// h = relu(x*dm @ Wxh + bxh); out[N,192] = [h, z] / (||[h,z]|| + 1e-6)
__global__ __launch_bounds__(256) void k_mmnorm(const void* __restrict__ X, const void* __restrict__ DM,
     const void* __restrict__ W, const void* __restrict__ bias,
     const float* __restrict__ zbuf, u16* __restrict__ out, const int* __restrict__ flags){
  constexpr int STEPS = 4, CT = 8, RTW = 5;   // K=128, DOUT=128, G=1; waves=1250, grid 313 (2 spare)
  int wid = blockIdx.x * 4 + (threadIdx.x >> 6);
  if (wid >= 1250) return;                    // wave-uniform, no syncs
  long chunk = wid;
  int lane = threadIdx.x & 63, n = lane & 15, q = lane >> 4;
  int fm = flags[0];

  short8 B[CT][STEPS];
  float bv[CT];
  #pragma unroll
  for (int ct = 0; ct < CT; ++ct){
    int col = ct * 16 + n;
    bv[ct] = ldx(bias, col, fm);
    #pragma unroll
    for (int s = 0; s < STEPS; ++s){
      short8 tt;
      #pragma unroll
      for (int j = 0; j < 8; ++j){
        int k = s * 32 + q * 8 + j;
        long wi = (long)k * 128 + col;
        tt[j] = fm ? (short)f2b(((const float*)W)[wi]) : (short)((const u16*)W)[wi];
      }
      B[ct][s] = tt;
    }
  }
  float4 z4 = *(const float4*)(zbuf + n * 4);   // z for cols 4n..4n+3 of the z-section
  float zz = zbuf[64];

  for (int rt = 0; rt < RTW; ++rt){
    long rowbase = (chunk * RTW + rt) * 16;
    long arow = rowbase + n;
    v4f acc[CT] = {};
    #pragma unroll
    for (int s = 0; s < STEPS; ++s){
      short8 a;
      long base = arow * 128 + s * 32 + q * 8;
      if (fm){
        const float* xp = (const float*)X + base;
        const float* dp = (const float*)DM + base;
        float4 x0 = *(const float4*)xp, x1 = *(const float4*)(xp + 4);
        float4 d0 = *(const float4*)dp, d1 = *(const float4*)(dp + 4);
        a[0] = (short)f2b(x0.x * d0.x); a[1] = (short)f2b(x0.y * d0.y);
        a[2] = (short)f2b(x0.z * d0.z); a[3] = (short)f2b(x0.w * d0.w);
        a[4] = (short)f2b(x1.x * d1.x); a[5] = (short)f2b(x1.y * d1.y);
        a[6] = (short)f2b(x1.z * d1.z); a[7] = (short)f2b(x1.w * d1.w);
      } else {
        short8 xv = *(const short8*)((const u16*)X + base);
        short8 dv = *(const short8*)((const u16*)DM + base);
        #pragma unroll
        for (int j = 0; j < 8; ++j) a[j] = (short)f2b(b2f((u16)xv[j]) * b2f((u16)dv[j]));
      }
      #pragma unroll
      for (int ct = 0; ct < CT; ++ct)
        acc[ct] = __builtin_amdgcn_mfma_f32_16x16x32_bf16(a, B[ct][s], acc[ct], 0, 0, 0);
    }
    // relu in place + per-row sum of squares (cross the 16 n-lanes of each q-group)
    #pragma unroll
    for (int r = 0; r < 4; ++r){
      float ss = 0.f;
      #pragma unroll
      for (int ct = 0; ct < CT; ++ct){
        float h = fmaxf(acc[ct][r] + bv[ct], 0.f);
        acc[ct][r] = h;
        ss = fmaf(h, h, ss);
      }
      ss += __shfl_xor(ss, 1); ss += __shfl_xor(ss, 2);
      ss += __shfl_xor(ss, 4); ss += __shfl_xor(ss, 8);
      float scale = 1.f / (sqrtf(ss + zz) + 1e-6f);
      long row = rowbase + q * 4 + r;
      u16* qp = out + row * 192;
      #pragma unroll
      for (int ct = 0; ct < CT; ++ct)
        qp[ct * 16 + n] = f2b(acc[ct][r] * scale);
      u32 zlo = (u32)f2b(z4.x * scale) | ((u32)f2b(z4.y * scale) << 16);
      u32 zhi = (u32)f2b(z4.z * scale) | ((u32)f2b(z4.w * scale) << 16);
      *(uint2*)(qp + 128 + n * 4) = make_uint2(zlo, zhi);
    }
  }
}

// ---------------- gumbel hard one-hot + where(non_label) ----------------
__global__ __launch_bounds__(256) void k_gumbel(const u16* __restrict__ yenc, const void* __restrict__ ug,
                         const void* __restrict__ ylab, const void* __restrict__ nonlab,
                         const int* __restrict__ flags, u16* __restrict__ y){
  int n = blockIdx.x * 256 + threadIdx.x;
  if (n >= NN) return;
  int fm = flags[0], mode = flags[1];
  bool nl;
  if      (mode == 1) nl = ((const int*)nonlab)[n] != 0;
  else if (mode == 3) nl = ((const float*)nonlab)[n] != 0.f;
  else if (mode == 2) nl = ((const u16*)nonlab)[n] != 0;
  else                nl = ((const unsigned char*)nonlab)[n] != 0;
  long base = (long)n * 32;
  if (nl){
    float best = -1e30f; int bi = 0;
    for (int j = 0; j < 32; ++j){
      float uu = ldx(ug, base + j, fm);
      float g = -logf(-logf(uu + 1e-10f) + 1e-10f);
      float v = b2f(yenc[base + j]) + g;
      if (v > best){ best = v; bi = j; }
    }
    for (int j = 0; j < 32; ++j) y[base + j] = (j == bi) ? (u16)0x3F80 : (u16)0;
  } else {
    for (int j = 0; j < 32; ++j)
      y[base + j] = fm ? f2b(((const float*)ylab)[base + j]) : ((const u16*)ylab)[base + j];
  }
}

// ---------------- tiny tail: r_graph -> hr -> mu/sigma -> z, plus ||z||^2 ----------------
__global__ void k_z(const float* __restrict__ accum,
                    const void* Whr, const void* bhr, const void* Wrh, const void* brh,
                    const void* Wmu, const void* bmu, const void* Wsig, const void* bsig,
                    const void* zeps, float* __restrict__ zout, const int* __restrict__ flags){
  __shared__ float hm[128], rg[128], hr[128], zl[64];
  int t = threadIdx.x, fm = flags[0];
  hm[t] = accum[t] * (1.0f / 100000.0f);
  __syncthreads();
  { float s = ldx(bhr, t, fm);
    for (int k = 0; k < 128; ++k) s = fmaf(hm[k], ldx(Whr, (long)k * 128 + t, fm), s);
    rg[t] = s; }
  __syncthreads();
  { float s = ldx(brh, t, fm);
    for (int k = 0; k < 128; ++k) s = fmaf(rg[k], ldx(Wrh, (long)k * 128 + t, fm), s);
    hr[t] = fmaxf(s, 0.f); }
  __syncthreads();
  if (t < 64){
    float m = ldx(bmu, t, fm), sv = ldx(bsig, t, fm);
    for (int k = 0; k < 128; ++k){
      float h = hr[k];
      m  = fmaf(h, ldx(Wmu,  (long)k * 64 + t, fm), m);
      sv = fmaf(h, ldx(Wsig, (long)k * 64 + t, fm), sv);
    }
    float sig = 0.1f + 0.9f / (1.f + expf(-sv));
    float z = fmaf(sig, ldx(zeps, t, fm), m);
    zl[t] = z; zout[t] = z;
  }
  __syncthreads();
  if (t == 0){ float ss = 0.f; for (int j = 0; j < 64; ++j) ss += zl[j] * zl[j]; zout[64] = ss; }
}

extern "C" void kernel_launch(void* const* d_in, const int* in_sizes, int n_in,
                              void* d_out, int out_size, void* d_ws, size_t ws_size,
                              hipStream_t stream){
  const void* x    = d_in[0];
  const void* ylab = d_in[1];
  const int*  ei   = (const int*)d_in[2];
  const void* ew   = d_in[3];
  const void* nonlab = d_in[4];
  const void* dm   = d_in[5];
  const void* ug   = d_in[6];
  const void* zeps = d_in[7];
  const void* Wg1 = d_in[8],  *bg1 = d_in[9];
  const void* Wg2 = d_in[10], *bg2 = d_in[11];
  const void* Wxy = d_in[12], *bxy = d_in[13];
  const void* Whr = d_in[14], *bhr = d_in[15];
  const void* Wrh = d_in[16], *brh = d_in[17];
  const void* Wmu = d_in[18], *bmu = d_in[19];
  const void* Wsg = d_in[20], *bsg = d_in[21];
  const void* Wxh = d_in[22], *bxh = d_in[23];
  const void* Wh2 = d_in[24], *bh2 = d_in[25];
  const void* Why = d_in[26], *bhy = d_in[27];

  char* ws = (char*)d_ws;
  size_t off = 0;
  auto alloc = [&](size_t bytes){ void* p = ws + off; off += (bytes + 511) & ~(size_t)511; return p; };
  int*   flags  = (int*)  alloc(256);
  int*   cnt    = (int*)  alloc((size_t)NN * 4);
  int*   rowptr = (int*)  alloc((size_t)(NN + 1) * 4);
  int*   part   = (int*)  alloc(1024 * 4);
  float* accum  = (float*)alloc(1024 * 4);        // [0:128) colsum, [128:192) z, [192] ||z||^2
  int*   rank   = (int*)  alloc((size_t)EE * 4);
  int2*  cpk    = (int2*) alloc((size_t)EE * 8);
  u16*   B0     = (u16*)  alloc((size_t)NN * 192 * 2);
  u16*   B1     = (u16*)  alloc((size_t)NN * 192 * 2);
  // yenc / ybuf live in B1's tail while B1's first [N,128] holds h_emb
  u16* yencB = B1 + (size_t)NN * 128;   // [N,32] bf16
  u16* ybuf  = B1 + (size_t)NN * 160;   // [N,32] bf16

  hipMemsetAsync(cnt, 0, (size_t)NN * 4, stream);
  hipMemsetAsync(accum, 0, 1024 * 4, stream);
  k_detect<<<1, 256, 0, stream>>>(x, nonlab, flags);
  // CSR build (shared by all 4 SpMMs)
  k_count  <<<EE / 256, 256, 0, stream>>>(ei, cnt, rank);
  k_scan1  <<<98, 256, 0, stream>>>(cnt, part);
  k_scan2  <<<1, 128, 0, stream>>>(part, rowptr, 98);
  k_scan3  <<<98, 256, 0, stream>>>(cnt, part, rowptr);
  k_scatter<<<EE / 256, 256, 0, stream>>>(ei, ew, rowptr, rank, cpk, flags);
  // pipeline
  k_spmm<128, true ><<<25000, 256, 0, stream>>>(x,  B0, rowptr, cpk, flags);                 // S1: x->B0
  k_mm<128,128,4,10,true ,0><<<313, 256, 0, stream>>>(B0, Wg1, bg1, B1, flags);              // h_emb->B1
  k_spmm<128, false><<<25000, 256, 0, stream>>>(B1, B0, rowptr, cpk, flags);                 // S2: B1->B0
  k_mm<128,32 ,2,5 ,false,0><<<313, 256, 0, stream>>>(B0, Wg2, bg2, yencB, flags);           // y_encode
  k_gumbel<<<(NN + 255) / 256, 256, 0, stream>>>(yencB, ug, ylab, nonlab, flags, ybuf);      // y
  k_mmsum<<<625, 256, 0, stream>>>(B1, ybuf, Wxy, bxy, accum, flags);                        // colsum(h_enc), fused
  k_z<<<1, 128, 0, stream>>>(accum, Whr, bhr, Wrh, brh, Wmu, bmu, Wsg, bsg, zeps, accum + 128, flags);
  k_mmnorm<<<313, 256, 0, stream>>>(x, dm, Wxh, bxh, accum + 128, B1, flags);                // h[N,192]->B1, fused norm
  k_spmm<192, false><<<25000, 256, 0, stream>>>(B1, B0, rowptr, cpk, flags);                 // S3: B1->B0
  k_mm<192,192,4,10,true ,0><<<469, 256, 0, stream>>>(B0, Wh2, bh2, B1, flags);              // h2->B1
  k_spmm<192, false><<<25000, 256, 0, stream>>>(B1, B0, rowptr, cpk, flags);                 // S4: B1->B0
  k_mm<192,32 ,2,5 ,false,1><<<313, 256, 0, stream>>>(B0, Why, bhy, d_out, flags);           // y_pred
}

// Round 7
// 1184.986 us; speedup vs baseline: 1.1053x; 1.1053x over previous
//
#include <hip/hip_runtime.h>
#include <hip/hip_bf16.h>

#define NN 100000
#define EE 1600000

typedef unsigned short u16;
typedef unsigned int   u32;
typedef short short8 __attribute__((ext_vector_type(8)));
typedef float v4f    __attribute__((ext_vector_type(4)));

__device__ __forceinline__ float b2f(u16 h){ u32 u = ((u32)h) << 16; return __builtin_bit_cast(float, u); }
__device__ __forceinline__ float lo2f(u32 u){ return __builtin_bit_cast(float, u << 16); }
__device__ __forceinline__ float hi2f(u32 u){ return __builtin_bit_cast(float, u & 0xffff0000u); }
__device__ __forceinline__ u16   f2b(float f){ __hip_bfloat16 h = __float2bfloat16(f); return __builtin_bit_cast(u16, h); }
__device__ __forceinline__ float ldx(const void* p, long i, int fm){
  return fm ? ((const float*)p)[i] : b2f(((const u16*)p)[i]);
}
__device__ __forceinline__ float i2f(int v){ return __builtin_bit_cast(float, v); }

// ---------------- dtype detection (parallel) ----------------
__global__ void k_detect(const void* __restrict__ x, const void* __restrict__ nonlab,
                         int* __restrict__ flags){
  __shared__ int s_bad, s_ni, s_nf, s_nb;
  int t = threadIdx.x;
  if (t == 0){ s_bad = 0; s_ni = 0; s_nf = 0; s_nb = 0; }
  __syncthreads();
  u32 w = ((const u32*)x)[t];
  u32 lo = w & 0xffffu, ex = (lo >> 7) & 0xffu;
  if (lo != 0u && (ex < 100u || ex > 140u)) atomicAdd(&s_bad, 1);
  if (t < 64){
    u32 v = ((const u32*)nonlab)[t];
    if (v > 1u) atomicAdd(&s_ni, 1);
    if (v != 0u && v != 0x3F800000u) atomicAdd(&s_nf, 1);
  }
  if (t < 128){
    u16 h = ((const u16*)nonlab)[t];
    if (h != 0 && h != 0x3F80) atomicAdd(&s_nb, 1);
  }
  __syncthreads();
  if (t == 0){
    flags[0] = (s_bad > 32) ? 1 : 0;
    flags[1] = (s_ni == 0) ? 1 : ((s_nf == 0) ? 3 : ((s_nb == 0) ? 2 : 0));
  }
}

// ---------------- CSR build ----------------
// count + per-edge rank (atomicAdd return value = rank within row)
__global__ void k_count(const int* __restrict__ ei, int* __restrict__ cnt, int* __restrict__ rank){
  int e = blockIdx.x * 256 + threadIdx.x;
  if (e < EE) rank[e] = atomicAdd(&cnt[ei[e]], 1);
}

#define SCAN_C 1024
__global__ void k_scan1(const int* __restrict__ cnt, int* __restrict__ part){
  __shared__ int red[256];
  int b = blockIdx.x, t = threadIdx.x;
  int base = b * SCAN_C + t * 4;
  int s = 0;
  #pragma unroll
  for (int j = 0; j < 4; ++j){ int i = base + j; if (i < NN) s += cnt[i]; }
  red[t] = s; __syncthreads();
  for (int o = 128; o; o >>= 1){ if (t < o) red[t] += red[t + o]; __syncthreads(); }
  if (t == 0) part[b] = red[0];
}
__global__ void k_scan2(int* __restrict__ part, int* __restrict__ rowptr, int nb){
  __shared__ int l[128];
  int t = threadIdx.x;
  int v = (t < nb) ? part[t] : 0;
  l[t] = v; __syncthreads();
  for (int o = 1; o < 128; o <<= 1){
    int x = (t >= o) ? l[t - o] : 0; __syncthreads();
    l[t] += x; __syncthreads();
  }
  if (t < nb) part[t] = l[t] - v;          // exclusive
  if (t == nb - 1) rowptr[NN] = l[t];      // total == EE
}
__global__ void k_scan3(const int* __restrict__ cnt, const int* __restrict__ part,
                        int* __restrict__ rowptr){
  __shared__ int lds[256];
  int b = blockIdx.x, t = threadIdx.x;
  int base = b * SCAN_C + t * 4;
  int v[4]; int s = 0;
  #pragma unroll
  for (int j = 0; j < 4; ++j){ int i = base + j; v[j] = (i < NN) ? cnt[i] : 0; s += v[j]; }
  lds[t] = s; __syncthreads();
  for (int o = 1; o < 256; o <<= 1){
    int x = (t >= o) ? lds[t - o] : 0; __syncthreads();
    lds[t] += x; __syncthreads();
  }
  int excl = lds[t] - s + part[b];
  #pragma unroll
  for (int j = 0; j < 4; ++j){
    int i = base + j;
    if (i < NN){ rowptr[i] = excl; excl += v[j]; }
  }
}
// atomic-free scatter: pos = rowptr[row] + rank[e]
__global__ void k_scatter(const int* __restrict__ ei, const void* __restrict__ ew,
                          const int* __restrict__ rowptr, const int* __restrict__ rank,
                          int2* __restrict__ cpk, const int* __restrict__ flags){
  int e = blockIdx.x * 256 + threadIdx.x;
  if (e >= EE) return;
  int fm = flags[0];
  int r = ei[e], c = ei[EE + e];
  int pos = rowptr[r] + rank[e];
  float wv = ldx(ew, e, fm);
  cpk[pos] = make_int2(c, __builtin_bit_cast(int, wv));
}

// ---------------- SpMM: one wave per row, 8 edges in flight + exact tail ----------------
template<int D, bool EXT>
__global__ __launch_bounds__(256) void k_spmm(const void* __restrict__ in, u16* __restrict__ out,
                       const int* __restrict__ rowptr, const int2* __restrict__ cpk,
                       const int* __restrict__ flags){
  int wid  = blockIdx.x * 4 + (threadIdx.x >> 6);
  int lane = threadIdx.x & 63;
  if (wid >= NN) return;
  int fm = EXT ? flags[0] : 0;
  int s = rowptr[wid], e = rowptr[wid + 1];
  float a0 = 0.f, a1 = 0.f, a2 = 0.f;
  int j = s;
  if (EXT && fm){
    const float* fin = (const float*)in;
    for (; j + 8 <= e; j += 8){
      int2 p[8];
      #pragma unroll
      for (int q = 0; q < 8; ++q) p[q] = cpk[j + q];
      float2 v[8];
      #pragma unroll
      for (int q = 0; q < 8; ++q) v[q] = *(const float2*)(fin + (long)p[q].x * D + 2 * lane);
      #pragma unroll
      for (int q = 0; q < 8; ++q){
        float wt = i2f(p[q].y);
        a0 = fmaf(wt, v[q].x, a0);
        a1 = fmaf(wt, v[q].y, a1);
      }
    }
    for (; j < e; ++j){
      int2 p = cpk[j]; float wt = i2f(p.y);
      float2 v = *(const float2*)(fin + (long)p.x * D + 2 * lane);
      a0 = fmaf(wt, v.x, a0); a1 = fmaf(wt, v.y, a1);
    }
  } else {
    const u16* uin = (const u16*)in;
    for (; j + 8 <= e; j += 8){
      int2 p[8];
      #pragma unroll
      for (int q = 0; q < 8; ++q) p[q] = cpk[j + q];
      u32 u[8]; u16 x2[8];
      #pragma unroll
      for (int q = 0; q < 8; ++q){
        long base = (long)p[q].x * D;
        u[q] = *(const u32*)(uin + base + 2 * lane);
        if (D == 192) x2[q] = uin[base + 128 + lane];
      }
      #pragma unroll
      for (int q = 0; q < 8; ++q){
        float wt = i2f(p[q].y);
        a0 = fmaf(wt, lo2f(u[q]), a0);
        a1 = fmaf(wt, hi2f(u[q]), a1);
        if (D == 192) a2 = fmaf(wt, b2f(x2[q]), a2);
      }
    }
    for (; j < e; ++j){
      int2 p = cpk[j]; float wt = i2f(p.y);
      long base = (long)p.x * D;
      u32 u = *(const u32*)(uin + base + 2 * lane);
      a0 = fmaf(wt, lo2f(u), a0);
      a1 = fmaf(wt, hi2f(u), a1);
      if (D == 192) a2 = fmaf(wt, b2f(uin[base + 128 + lane]), a2);
    }
  }
  u16* q = out + (long)wid * D;
  *(u32*)(q + 2 * lane) = (u32)f2b(a0) | ((u32)f2b(a1) << 16);
  if (D == 192) q[128 + lane] = f2b(a2);
}

// ---------------- generic MFMA GEMM (AMODE variants, round-4 measured form) ----------------
template<int K, int DOUT, int CT, int RTW, bool RELU, int AMODE, int OMODE>
__global__ __launch_bounds__(256) void k_mm(const u16* __restrict__ A, const void* __restrict__ A2,
     const void* __restrict__ A3, const void* __restrict__ W, const void* __restrict__ bias,
     void* __restrict__ outv, const int* __restrict__ flags){
  constexpr int STEPS = K / 32;
  constexpr int G = DOUT / (16 * CT);
  constexpr int CHUNKS = 6250 / RTW;
  int wid = blockIdx.x * 4 + (threadIdx.x >> 6);
  if (wid >= G * CHUNKS) return;          // wave-uniform exit
  int g = wid % G; long chunk = wid / G;
  int lane = threadIdx.x & 63, n = lane & 15, q = lane >> 4;
  int colOff = g * CT * 16;
  int fm = flags[0];

  short8 B[CT][STEPS];
  float bv[CT];
  #pragma unroll
  for (int ct = 0; ct < CT; ++ct){
    int col = colOff + ct * 16 + n;
    bv[ct] = ldx(bias, col, fm);
    #pragma unroll
    for (int s = 0; s < STEPS; ++s){
      short8 t;
      #pragma unroll
      for (int j = 0; j < 8; ++j){
        int k = s * 32 + q * 8 + j;
        long wi = (long)k * DOUT + col;
        t[j] = fm ? (short)f2b(((const float*)W)[wi]) : (short)((const u16*)W)[wi];
      }
      B[ct][s] = t;
    }
  }

  for (int rt = 0; rt < RTW; ++rt){
    long rowbase = (chunk * RTW + rt) * 16;
    long arow = rowbase + n;
    v4f acc[CT] = {};
    #pragma unroll
    for (int s = 0; s < STEPS; ++s){
      short8 a;
      if (AMODE == 0){
        a = *(const short8*)(A + arow * K + s * 32 + q * 8);
      } else { // AMODE==1: x*dm external
        long base = arow * 128 + s * 32 + q * 8;
        if (fm){
          const float* xp = (const float*)A2 + base;
          const float* dp = (const float*)A3 + base;
          float4 x0 = *(const float4*)xp, x1 = *(const float4*)(xp + 4);
          float4 d0 = *(const float4*)dp, d1 = *(const float4*)(dp + 4);
          a[0] = (short)f2b(x0.x * d0.x); a[1] = (short)f2b(x0.y * d0.y);
          a[2] = (short)f2b(x0.z * d0.z); a[3] = (short)f2b(x0.w * d0.w);
          a[4] = (short)f2b(x1.x * d1.x); a[5] = (short)f2b(x1.y * d1.y);
          a[6] = (short)f2b(x1.z * d1.z); a[7] = (short)f2b(x1.w * d1.w);
        } else {
          short8 xv = *(const short8*)((const u16*)A2 + base);
          short8 dv = *(const short8*)((const u16*)A3 + base);
          #pragma unroll
          for (int j = 0; j < 8; ++j) a[j] = (short)f2b(b2f((u16)xv[j]) * b2f((u16)dv[j]));
        }
      }
      #pragma unroll
      for (int ct = 0; ct < CT; ++ct)
        acc[ct] = __builtin_amdgcn_mfma_f32_16x16x32_bf16(a, B[ct][s], acc[ct], 0, 0, 0);
    }
    long orow = rowbase + q * 4;
    #pragma unroll
    for (int ct = 0; ct < CT; ++ct){
      int col = colOff + ct * 16 + n;
      #pragma unroll
      for (int r = 0; r < 4; ++r){
        float v = acc[ct][r] + bv[ct];
        if (RELU) v = fmaxf(v, 0.f);
        long oi = (orow + r) * (long)DOUT + col;
        if (OMODE == 1){
          if (fm) ((float*)outv)[oi] = v; else ((u16*)outv)[oi] = f2b(v);
        } else {
          ((u16*)outv)[oi] = f2b(v);
        }
      }
    }
  }
}

// ---------------- fused encoder mm + column-sum (h_enc never materialized) ----------------
__global__ __launch_bounds__(256) void k_mmsum(const u16* __restrict__ A, const u16* __restrict__ Y,
     const void* __restrict__ W, const void* __restrict__ bias,
     float* __restrict__ accum, const int* __restrict__ flags){
  constexpr int STEPS = 5, CT = 4, RTW = 5;   // K=160, DOUT=128, G=2; waves = 2500, grid 625
  __shared__ float cs[128];
  int t = threadIdx.x;
  if (t < 128) cs[t] = 0.f;
  __syncthreads();
  int wid = blockIdx.x * 4 + (t >> 6);
  int g = wid & 1; long chunk = wid >> 1;
  int lane = t & 63, n = lane & 15, q = lane >> 4;
  int colOff = g * 64;
  int fm = flags[0];

  short8 B[CT][STEPS];
  float bv[CT];
  #pragma unroll
  for (int ct = 0; ct < CT; ++ct){
    int col = colOff + ct * 16 + n;
    bv[ct] = ldx(bias, col, fm);
    #pragma unroll
    for (int s = 0; s < STEPS; ++s){
      short8 tt;
      #pragma unroll
      for (int j = 0; j < 8; ++j){
        int k = s * 32 + q * 8 + j;
        long wi = (long)k * 128 + col;
        tt[j] = fm ? (short)f2b(((const float*)W)[wi]) : (short)((const u16*)W)[wi];
      }
      B[ct][s] = tt;
    }
  }

  float csum[CT] = {0.f, 0.f, 0.f, 0.f};
  for (int rt = 0; rt < RTW; ++rt){
    long rowbase = (chunk * RTW + rt) * 16;
    long arow = rowbase + n;
    v4f acc[CT] = {};
    #pragma unroll
    for (int s = 0; s < STEPS; ++s){
      short8 a;
      if (s < 4) a = *(const short8*)(A + arow * 128 + s * 32 + q * 8);
      else       a = *(const short8*)(Y + arow * 32 + q * 8);
      #pragma unroll
      for (int ct = 0; ct < CT; ++ct)
        acc[ct] = __builtin_amdgcn_mfma_f32_16x16x32_bf16(a, B[ct][s], acc[ct], 0, 0, 0);
    }
    #pragma unroll
    for (int ct = 0; ct < CT; ++ct){
      #pragma unroll
      for (int r = 0; r < 4; ++r)
        csum[ct] += fmaxf(acc[ct][r] + bv[ct], 0.f);
    }
  }
  #pragma unroll
  for (int ct = 0; ct < CT; ++ct){
    float v = csum[ct];
    v += __shfl_xor(v, 16);
    v += __shfl_xor(v, 32);
    if (q == 0) atomicAdd(&cs[colOff + ct * 16 + n], v);
  }
  __syncthreads();
  if (t < 128) atomicAdd(&accum[t], cs[t]);
}

// ---------------- gumbel hard one-hot + where(non_label) ----------------
__global__ __launch_bounds__(256) void k_gumbel(const u16* __restrict__ yenc, const void* __restrict__ ug,
                         const void* __restrict__ ylab, const void* __restrict__ nonlab,
                         const int* __restrict__ flags, u16* __restrict__ y){
  int n = blockIdx.x * 256 + threadIdx.x;
  if (n >= NN) return;
  int fm = flags[0], mode = flags[1];
  bool nl;
  if      (mode == 1) nl = ((const int*)nonlab)[n] != 0;
  else if (mode == 3) nl = ((const float*)nonlab)[n] != 0.f;
  else if (mode == 2) nl = ((const u16*)nonlab)[n] != 0;
  else                nl = ((const unsigned char*)nonlab)[n] != 0;
  long base = (long)n * 32;
  if (nl){
    float best = -1e30f; int bi = 0;
    for (int j = 0; j < 32; ++j){
      float uu = ldx(ug, base + j, fm);
      float g = -logf(-logf(uu + 1e-10f) + 1e-10f);
      float v = b2f(yenc[base + j]) + g;
      if (v > best){ best = v; bi = j; }
    }
    for (int j = 0; j < 32; ++j) y[base + j] = (j == bi) ? (u16)0x3F80 : (u16)0;
  } else {
    for (int j = 0; j < 32; ++j)
      y[base + j] = fm ? f2b(((const float*)ylab)[base + j]) : ((const u16*)ylab)[base + j];
  }
}

// ---------------- tiny tail: r_graph -> hr -> mu/sigma -> z, plus ||z||^2 ----------------
__global__ void k_z(const float* __restrict__ accum,
                    const void* Whr, const void* bhr, const void* Wrh, const void* brh,
                    const void* Wmu, const void* bmu, const void* Wsig, const void* bsig,
                    const void* zeps, float* __restrict__ zout, const int* __restrict__ flags){
  __shared__ float hm[128], rg[128], hr[128], zl[64];
  int t = threadIdx.x, fm = flags[0];
  hm[t] = accum[t] * (1.0f / 100000.0f);
  __syncthreads();
  { float s = ldx(bhr, t, fm);
    for (int k = 0; k < 128; ++k) s = fmaf(hm[k], ldx(Whr, (long)k * 128 + t, fm), s);
    rg[t] = s; }
  __syncthreads();
  { float s = ldx(brh, t, fm);
    for (int k = 0; k < 128; ++k) s = fmaf(rg[k], ldx(Wrh, (long)k * 128 + t, fm), s);
    hr[t] = fmaxf(s, 0.f); }
  __syncthreads();
  if (t < 64){
    float m = ldx(bmu, t, fm), sv = ldx(bsig, t, fm);
    for (int k = 0; k < 128; ++k){
      float h = hr[k];
      m  = fmaf(h, ldx(Wmu,  (long)k * 64 + t, fm), m);
      sv = fmaf(h, ldx(Wsig, (long)k * 64 + t, fm), sv);
    }
    float sig = 0.1f + 0.9f / (1.f + expf(-sv));
    float z = fmaf(sig, ldx(zeps, t, fm), m);
    zl[t] = z; zout[t] = z;
  }
  __syncthreads();
  if (t == 0){ float ss = 0.f; for (int j = 0; j < 64; ++j) ss += zl[j] * zl[j]; zout[64] = ss; }
}

// ---------------- row-normalize: H[N,128] (relu'd) + z -> out[N,192] ----------------
__global__ __launch_bounds__(256) void k_norm(const u16* __restrict__ H, const float* __restrict__ zbuf,
                                              u16* __restrict__ out){
  int wid = blockIdx.x * 4 + (threadIdx.x >> 6);
  int lane = threadIdx.x & 63;
  if (wid >= NN) return;
  u32 hv = *(const u32*)(H + (long)wid * 128 + 2 * lane);
  float h0 = lo2f(hv), h1 = hi2f(hv);
  float ss = h0 * h0 + h1 * h1;
  for (int o = 32; o; o >>= 1) ss += __shfl_xor(ss, o);
  float zz = zbuf[64];
  float zv = zbuf[lane];
  float scale = 1.f / (sqrtf(ss + zz) + 1e-6f);
  u16* q = out + (long)wid * 192;
  *(u32*)(q + 2 * lane) = (u32)f2b(h0 * scale) | ((u32)f2b(h1 * scale) << 16);
  q[128 + lane] = f2b(zv * scale);
}

extern "C" void kernel_launch(void* const* d_in, const int* in_sizes, int n_in,
                              void* d_out, int out_size, void* d_ws, size_t ws_size,
                              hipStream_t stream){
  const void* x    = d_in[0];
  const void* ylab = d_in[1];
  const int*  ei   = (const int*)d_in[2];
  const void* ew   = d_in[3];
  const void* nonlab = d_in[4];
  const void* dm   = d_in[5];
  const void* ug   = d_in[6];
  const void* zeps = d_in[7];
  const void* Wg1 = d_in[8],  *bg1 = d_in[9];
  const void* Wg2 = d_in[10], *bg2 = d_in[11];
  const void* Wxy = d_in[12], *bxy = d_in[13];
  const void* Whr = d_in[14], *bhr = d_in[15];
  const void* Wrh = d_in[16], *brh = d_in[17];
  const void* Wmu = d_in[18], *bmu = d_in[19];
  const void* Wsg = d_in[20], *bsg = d_in[21];
  const void* Wxh = d_in[22], *bxh = d_in[23];
  const void* Wh2 = d_in[24], *bh2 = d_in[25];
  const void* Why = d_in[26], *bhy = d_in[27];

  char* ws = (char*)d_ws;
  size_t off = 0;
  auto alloc = [&](size_t bytes){ void* p = ws + off; off += (bytes + 511) & ~(size_t)511; return p; };
  int*   flags  = (int*)  alloc(256);
  int*   cnt    = (int*)  alloc((size_t)NN * 4);
  int*   rowptr = (int*)  alloc((size_t)(NN + 1) * 4);
  int*   part   = (int*)  alloc(1024 * 4);
  float* accum  = (float*)alloc(1024 * 4);        // [0:128) colsum, [128:192) z, [192] ||z||^2
  int*   rank   = (int*)  alloc((size_t)EE * 4);
  int2*  cpk    = (int2*) alloc((size_t)EE * 8);
  u16*   B0     = (u16*)  alloc((size_t)NN * 192 * 2);
  u16*   B1     = (u16*)  alloc((size_t)NN * 192 * 2);
  // yenc / ybuf live in B1's tail while B1's first [N,128] holds h_emb
  u16* yencB = B1 + (size_t)NN * 128;   // [N,32] bf16
  u16* ybuf  = B1 + (size_t)NN * 160;   // [N,32] bf16

  hipMemsetAsync(cnt, 0, (size_t)NN * 4, stream);
  hipMemsetAsync(accum, 0, 1024 * 4, stream);
  k_detect<<<1, 256, 0, stream>>>(x, nonlab, flags);
  // CSR build (shared by all 4 SpMMs)
  k_count  <<<EE / 256, 256, 0, stream>>>(ei, cnt, rank);
  k_scan1  <<<98, 256, 0, stream>>>(cnt, part);
  k_scan2  <<<1, 128, 0, stream>>>(part, rowptr, 98);
  k_scan3  <<<98, 256, 0, stream>>>(cnt, part, rowptr);
  k_scatter<<<EE / 256, 256, 0, stream>>>(ei, ew, rowptr, rank, cpk, flags);
  // pipeline
  k_spmm<128, true ><<<25000, 256, 0, stream>>>(x,  B0, rowptr, cpk, flags);                 // S1: x->B0
  k_mm<128,128,4,10,true ,0,0><<<313, 256, 0, stream>>>(B0, nullptr, nullptr, Wg1, bg1, B1, flags);   // h_emb->B1
  k_spmm<128, false><<<25000, 256, 0, stream>>>(B1, B0, rowptr, cpk, flags);                 // S2: B1->B0
  k_mm<128,32 ,2,5 ,false,0,0><<<313, 256, 0, stream>>>(B0, nullptr, nullptr, Wg2, bg2, yencB, flags); // y_encode
  k_gumbel<<<(NN + 255) / 256, 256, 0, stream>>>(yencB, ug, ylab, nonlab, flags, ybuf);      // y
  k_mmsum<<<625, 256, 0, stream>>>(B1, ybuf, Wxy, bxy, accum, flags);                        // colsum(h_enc), fused
  k_z<<<1, 128, 0, stream>>>(accum, Whr, bhr, Wrh, brh, Wmu, bmu, Wsg, bsg, zeps, accum + 128, flags);
  k_mm<128,128,4,10,true ,1,0><<<313, 256, 0, stream>>>(nullptr, x, dm, Wxh, bxh, B0, flags);         // H=relu(xd@Wxh)->B0
  k_norm<<<25000, 256, 0, stream>>>(B0, accum + 128, B1);                                    // h [N,192]->B1
  k_spmm<192, false><<<25000, 256, 0, stream>>>(B1, B0, rowptr, cpk, flags);                 // S3: B1->B0
  k_mm<192,192,4,10,true ,0,0><<<469, 256, 0, stream>>>(B0, nullptr, nullptr, Wh2, bh2, B1, flags);   // h2->B1
  k_spmm<192, false><<<25000, 256, 0, stream>>>(B1, B0, rowptr, cpk, flags);                 // S4: B1->B0
  k_mm<192,32 ,2,5 ,false,0,1><<<313, 256, 0, stream>>>(B0, nullptr, nullptr, Why, bhy, d_out, flags); // y_pred
}